// Round 3
// baseline (505.097 us; speedup 1.0000x reference)
//
#include <hip/hip_runtime.h>
#include <hip/hip_bf16.h>
#include <math.h>

#define NN 50000
#define IN_DIM 1024
#define EE 100000
#define NUM_REL 40
#define HEADS 4
#define OUT_D 200
#define HID 800
#define BB 8192
#define SLOT_CAP 16384
#define SRC_CAP 50176   // max gathered rows (>= NN rounded to tile)
#define WT_COLS 896     // 800 W cols + 8 Wa cols + pad

typedef __attribute__((ext_vector_type(8))) short short8;
typedef __attribute__((ext_vector_type(4))) float f32x4;

__device__ inline unsigned short f2bf(float f) {
    unsigned int u = __float_as_uint(f);
    u += 0x7FFF + ((u >> 16) & 1);
    return (unsigned short)(u >> 16);
}
__device__ inline float bf2f(unsigned short s) {
    return __uint_as_float(((unsigned int)s) << 16);
}
__device__ inline void gl2lds16(const unsigned short* g, unsigned short* l) {
    __builtin_amdgcn_global_load_lds(
        (const __attribute__((address_space(1))) void*)g,
        (__attribute__((address_space(3))) void*)l, 16, 0, 0);
}

// wave-aggregated compaction: one atomicAdd per wave instead of per winner.
__device__ inline int wave_compact(bool won, int* ctr) {
    unsigned long long m = __ballot(won);
    if (!m) return -1;
    int lane = threadIdx.x & 63;
    int leader = __ffsll((long long)m) - 1;
    int base = 0;
    if (lane == leader) base = atomicAdd(ctr, __popcll(m));
    base = __shfl(base, leader, 64);
    return won ? base + __popcll(m & ((1ull << lane) - 1)) : -1;
}

// ---------------- fused: init (blocks 0..195) | Wa/prel (blocks 196..) ----------------
#define INIT_BLOCKS 196
__global__ __launch_bounds__(256) void k_init_wa(int* slot_of_node, int* xrow_of_node,
                                                 int* deg, int* counters,
                                                 const float* W, const float* a_src,
                                                 const float* a_dst, const float* a_rel,
                                                 const float* rel_feat, float* Wa, float* prel) {
    int b = blockIdx.x;
    if (b < INIT_BLOCKS) {
        int i = b * 256 + threadIdx.x;
        if (i < NN) { slot_of_node[i] = -1; xrow_of_node[i] = -1; }
        if (i < SLOT_CAP) deg[i] = 0;
        if (i < 8) counters[i] = 0;
        return;
    }
    int wid = (b - INIT_BLOCKS) * 4 + (threadIdx.x >> 6);
    int lane = threadIdx.x & 63;
    if (wid >= IN_DIM * 8 + NUM_REL * HEADS) return;
    float acc = 0.f;
    int d = lane * 4;
    if (d < OUT_D) {
        const float* row;
        const float* a;
        if (wid < IN_DIM * 8) {
            int k = wid >> 3, c = wid & 7;
            int h = c & 3;
            row = W + (size_t)k * HID + h * OUT_D;
            a = ((c < 4) ? a_src : a_dst) + h * OUT_D;
        } else {
            int j = wid - IN_DIM * 8;
            int r = j >> 2, h = j & 3;
            row = rel_feat + (size_t)r * HID + h * OUT_D;
            a = a_rel + h * OUT_D;
        }
        float4 wv = *(const float4*)(row + d);
        float4 av = *(const float4*)(a + d);
        acc = wv.x * av.x + wv.y * av.y + wv.z * av.z + wv.w * av.w;
    }
    for (int off = 32; off; off >>= 1) acc += __shfl_down(acc, off, 64);
    if (lane == 0) {
        if (wid < IN_DIM * 8) Wa[wid] = acc;
        else prel[wid - IN_DIM * 8] = acc;
    }
}

// compact score nodes (src_ids ∪ dst_ids) -> slots; record unique score list
__global__ void k_build_slots(const int* src_ids, const int* dst_ids,
                              int* slot_of_node, int* counters, int* scorelist) {
    int i = blockIdx.x * 256 + threadIdx.x;
    bool valid = i < 2 * BB;
    int n = 0;
    bool won = false;
    if (valid) {
        n = (i < BB) ? src_ids[i] : dst_ids[i - BB];
        if (slot_of_node[n] == -1)
            won = (atomicCAS(&slot_of_node[n], -1, -2) == -1);
    }
    int s = wave_compact(won, &counters[0]);
    if (won) {
        slot_of_node[n] = s;
        scorelist[s] = n;
    }
}

// survivor pass: compact srcs of surviving edges (xrows 0..nsrc), per-slot degree
__global__ void k_edge0(const int* ei, const int* slot_of_node,
                        int* xrow_of_node, int* counters, int* rows, int* deg) {
    int e = blockIdx.x * 256 + threadIdx.x;
    bool valid = e < EE;
    int slot = -1, sn = 0;
    if (valid) {
        int dn = ei[EE + e];
        slot = slot_of_node[dn];
    }
    bool surv = valid && slot >= 0;
    bool won = false;
    if (surv) {
        sn = ei[e];
        if (xrow_of_node[sn] == -1)
            won = (atomicCAS(&xrow_of_node[sn], -1, -2) == -1);
    }
    int t = wave_compact(won, &counters[1]);
    if (won) {
        rows[t] = sn;
        xrow_of_node[sn] = t;
    }
    if (surv) atomicAdd(&deg[slot], 1);
}

// fused: scan (block 0) | tail (blocks 1..64) | Wt transpose+cast (blocks 65..288)
__global__ __launch_bounds__(256) void k_tail_scan_wt(const int* scorelist, int* xrow_of_node,
                                                      int* counters, int* rows,
                                                      const int* deg, int* base, int* cursor,
                                                      const float* W, const float* Wa,
                                                      unsigned short* Wt) {
    int t = threadIdx.x;
    if (blockIdx.x == 0) {
        __shared__ int pref[257];
        int s = 0;
        const int4* dv = (const int4*)(deg + t * (SLOT_CAP / 256));
        for (int i = 0; i < SLOT_CAP / 256 / 4; ++i) {
            int4 v = dv[i];
            s += v.x + v.y + v.z + v.w;
        }
        pref[t + 1] = s;
        if (t == 0) pref[0] = 0;
        __syncthreads();
        if (t == 0)
            for (int i = 1; i <= 256; ++i) pref[i] += pref[i - 1];
        __syncthreads();
        int r = pref[t];
        for (int i = 0; i < SLOT_CAP / 256; ++i) {
            int idx = t * (SLOT_CAP / 256) + i;
            base[idx] = r;
            cursor[idx] = r;
            r += deg[idx];
        }
        return;
    }
    if (blockIdx.x <= 64) {
        int i = (blockIdx.x - 1) * 256 + t;
        bool valid = i < counters[0];
        int n = 0;
        bool won = false;
        if (valid) {
            n = scorelist[i];
            won = (xrow_of_node[n] < 0);
        }
        int tt = wave_compact(won, &counters[3]);
        if (won) {
            int xr = counters[1] + tt;   // counters[1] stable: edge0 completed
            xrow_of_node[n] = xr;
            rows[xr] = n;
        }
        return;
    }
    // Wt transpose: W[k][c] (f32) -> Wt[c][k] (bf16), cols 800..807 = Wa
    __shared__ float tile[64][65];
    int b = blockIdx.x - 65;                 // 0..223 = 16 k-blocks x 14 col-blocks
    int k0 = (b & 15) * 64, c0 = (b >> 4) * 64;
    {
        int kk = t >> 2, cc = (t & 3) * 16;
        for (int i = 0; i < 16; ++i) {
            int c = c0 + cc + i;
            float v = 0.f;
            if (c < HID) v = W[(size_t)(k0 + kk) * HID + c];
            else if (c < HID + 8) v = Wa[(size_t)(k0 + kk) * 8 + (c - HID)];
            tile[cc + i][kk] = v;
        }
    }
    __syncthreads();
    {
        int cc = t >> 2, kk = (t & 3) * 16;
        unsigned short o[16];
        for (int i = 0; i < 16; ++i) o[i] = f2bf(tile[cc][kk + i]);
        *(short8*)(Wt + (size_t)(c0 + cc) * IN_DIM + k0 + kk) = *(short8*)o;
        *(short8*)(Wt + (size_t)(c0 + cc) * IN_DIM + k0 + kk + 8) = *(short8*)(o + 8);
    }
}

// MFMA bf16 GEMM with FUSED gather+cast on the A path (xg eliminated).
// 128x128 tile, 256 threads (4 waves, 64x64 each), BK=64, double-buffered
// LDS (64 KB -> 2 blocks/CU). A: per tile each thread loads 8x float4
// directly from node_emb[rows[.]], cvt to bf16, ds_write_b128 into the
// fragment-ordered layout. B: global_load_lds from Wt. Counted gates:
// vmcnt(4) = A's 8 reg-loads done (B's 4 gl2lds still in flight);
// vmcnt(0)+lgkmcnt(0) at publish. XCD swizzle: 2744 blocks = 49 groups of
// 56; XCD x sweeps row-panel g*8+x across all 7 col-tiles (A panel 512 KB
// f32 stays in its L2).
#define GBM 128
#define GBN 128
#define GBK 64

#define ALOAD(K0) do {                                                  \
    av[0] = *(const float4*)(ax0 + (K0));                               \
    av[1] = *(const float4*)(ax0 + (K0) + 4);                           \
    av[2] = *(const float4*)(ax1 + (K0));                               \
    av[3] = *(const float4*)(ax1 + (K0) + 4);                           \
    av[4] = *(const float4*)(ax0 + (K0) + 32);                          \
    av[5] = *(const float4*)(ax0 + (K0) + 36);                          \
    av[6] = *(const float4*)(ax1 + (K0) + 32);                          \
    av[7] = *(const float4*)(ax1 + (K0) + 36);                          \
} while (0)

#define AWRITE(AS) do {                                                 \
    unsigned short o[8];                                                \
    _Pragma("unroll")                                                   \
    for (int q = 0; q < 4; ++q) {                                       \
        o[0] = f2bf(av[2*q].x); o[1] = f2bf(av[2*q].y);                 \
        o[2] = f2bf(av[2*q].z); o[3] = f2bf(av[2*q].w);                 \
        o[4] = f2bf(av[2*q+1].x); o[5] = f2bf(av[2*q+1].y);             \
        o[6] = f2bf(av[2*q+1].z); o[7] = f2bf(av[2*q+1].w);             \
        *(short8*)&(AS)[(size_t)(q * 256 + t) * 8] = *(short8*)o;       \
    }                                                                   \
} while (0)

#define BSTAGE(BS, K0) do {                                             \
    gl2lds16(bP0 + (K0),      (BS) + (size_t)(0 * 256 + t) * 8);        \
    gl2lds16(bP1 + (K0),      (BS) + (size_t)(1 * 256 + t) * 8);        \
    gl2lds16(bP0 + (K0) + 32, (BS) + (size_t)(2 * 256 + t) * 8);        \
    gl2lds16(bP1 + (K0) + 32, (BS) + (size_t)(3 * 256 + t) * 8);        \
} while (0)

#define COMPUTE(AS, BS) do {                                            \
    _Pragma("unroll")                                                   \
    for (int s = 0; s < 2; ++s) {                                       \
        short8 af[4], bf4[4];                                           \
        _Pragma("unroll")                                               \
        for (int i = 0; i < 4; ++i)                                     \
            af[i] = *(const short8*)&(AS)[(size_t)(s * 512 + (ga + i) * 64 + lane) * 8]; \
        _Pragma("unroll")                                               \
        for (int j = 0; j < 4; ++j)                                     \
            bf4[j] = *(const short8*)&(BS)[(size_t)(s * 512 + (gb + j) * 64 + lane) * 8]; \
        __builtin_amdgcn_s_setprio(1);                                  \
        _Pragma("unroll")                                               \
        for (int i = 0; i < 4; ++i)                                     \
            _Pragma("unroll")                                           \
            for (int j = 0; j < 4; ++j)                                 \
                acc[i][j] = __builtin_amdgcn_mfma_f32_16x16x32_bf16(af[i], bf4[j], acc[i][j], 0, 0, 0); \
        __builtin_amdgcn_s_setprio(0);                                  \
    }                                                                   \
} while (0)

#define WAIT_A  asm volatile("s_waitcnt vmcnt(4)" ::: "memory")
#define PUBLISH asm volatile("s_waitcnt vmcnt(0) lgkmcnt(0)" ::: "memory")
#define BARX    asm volatile("s_barrier" ::: "memory")

__global__ __launch_bounds__(256) void k_hgemm(const float* x, const int* rows,
                                               const unsigned short* Wt,
                                               const int* counters, unsigned short* h_src,
                                               float* sS, float* sD) {
    int nsrc = counters[1];
    int nneed = nsrc + counters[3];
    int lin = blockIdx.x + 7 * blockIdx.y;   // 0..2743 = 49 groups of 56
    int g = lin / 56, r = lin % 56;
    int rowb = g * 8 + (r & 7);              // 0..391
    int colb = r >> 3;                       // 0..6
    int col0 = colb * GBN;
    int row0 = rowb * GBM;
    int rowlim = (col0 == 768) ? nneed : nsrc;
    if (row0 >= rowlim) return;
    __shared__ unsigned short As0[GBM * GBK];  // 16 KB each
    __shared__ unsigned short As1[GBM * GBK];
    __shared__ unsigned short Bs0[GBN * GBK];
    __shared__ unsigned short Bs1[GBN * GBK];
    int t = threadIdx.x;
    int crow = ((t >> 6) << 4) + (t & 15);   // 0..63
    int coff = ((t >> 4) & 3) << 3;          // 0,8,16,24
    // A-path: gathered node rows (clamped for partially-active tiles)
    int lim = nneed - 1;
    int n0 = rows[min(row0 + crow, lim)];
    int n1 = rows[min(row0 + crow + 64, lim)];
    const float* ax0 = x + (size_t)n0 * IN_DIM + coff;
    const float* ax1 = x + (size_t)n1 * IN_DIM + coff;
    const unsigned short* bP0 = Wt + (size_t)(col0 + crow) * IN_DIM + coff;
    const unsigned short* bP1 = bP0 + (size_t)64 * IN_DIM;
    int w = t >> 6, lane = t & 63;
    int ga = (w >> 1) * 4, gb = (w & 1) * 4;
    int wr = (w >> 1) * 64, wc = (w & 1) * 64;
    int fm = lane & 15, fq = lane >> 4;
    float4 av[8];
    f32x4 acc[4][4] = {};
    // prologue: tile 0
    ALOAD(0);
    BSTAGE(Bs0, 0);
    WAIT_A;
    AWRITE(As0);
    PUBLISH;
    BARX;
#pragma unroll 1
    for (int kk = 0; kk < 16; kk += 2) {
        ALOAD((kk + 1) * 64);
        BSTAGE(Bs1, (kk + 1) * 64);
        COMPUTE(As0, Bs0);
        BARX;                     // all waves done reading buf0
        WAIT_A;
        AWRITE(As1);
        PUBLISH;
        BARX;                     // buf1 published
        if (kk < 14) {
            ALOAD((kk + 2) * 64);
            BSTAGE(Bs0, (kk + 2) * 64);
        }
        COMPUTE(As1, Bs1);
        BARX;                     // all waves done reading buf1
        if (kk < 14) {
            WAIT_A;
            AWRITE(As0);
            PUBLISH;
            BARX;                 // buf0 published
        }
    }
#pragma unroll
    for (int i = 0; i < 4; ++i) {
#pragma unroll
        for (int j = 0; j < 4; ++j) {
            int gcol = col0 + wc + j * 16 + fm;
            if (gcol >= HID + 8) continue;
#pragma unroll
            for (int rr = 0; rr < 4; ++rr) {
                int grow = row0 + wr + i * 16 + fq * 4 + rr;
                float v = acc[i][j][rr];
                if (gcol < HID) {
                    if (grow < nsrc) h_src[(size_t)grow * HID + gcol] = f2bf(v);
                } else if (grow < nneed) {
                    int c = gcol - HID;
                    if (c < 4) sS[grow * 4 + c] = v;
                    else sD[grow * 4 + (c - 4)] = v;
                }
            }
        }
    }
}

// place surviving edges into CSR, computing logits at final position
__global__ void k_place(const int* ei, const int* etype, const int* slot_of_node,
                        const int* xrow_of_node, int* cursor,
                        const float* sS, const float* sD, const float* prel,
                        float* clogit, int* tlist) {
    int e = blockIdx.x * 256 + threadIdx.x;
    if (e >= EE) return;
    int dn = ei[EE + e];
    int slot = slot_of_node[dn];
    if (slot < 0) return;
    int sn = ei[e];
    int r = etype[e];
    int xs = xrow_of_node[sn];
    int xd = xrow_of_node[dn];
    int pos = atomicAdd(&cursor[slot], 1);
    tlist[pos] = xs;
    float4 lg;
    float* lp = (float*)&lg;
#pragma unroll
    for (int h = 0; h < 4; ++h) {
        float v = sS[xs * 4 + h] + sD[xd * 4 + h] + prel[r * 4 + h];
        lp[h] = v > 0.f ? v : 0.2f * v;
    }
    *(float4*)&clogit[(size_t)pos * 4] = lg;
}

// per-dst-slot softmax + aggregate: one block per slot; 200 lanes x 4 elems,
// ushort4 (8B) h_src loads
__global__ __launch_bounds__(256) void k_aggregate(const int* counters, const int* base,
                                                   const int* deg, const int* tlist,
                                                   const float* clogit,
                                                   const unsigned short* h_src, const float* bias,
                                                   float* refined) {
    int b = blockIdx.x;
    if (b >= counters[0]) return;
    int beg = base[b], d = deg[b];
    __shared__ float m4[4], den4[4];
    __shared__ float alpha[64][4];
    __shared__ int tsl[64];
    int t = threadIdx.x;
    if (t < 4) {
        float m = -3e38f;
        for (int j = 0; j < d; ++j)
            m = fmaxf(m, clogit[(size_t)(beg + j) * 4 + t]);
        float s = 0.f;
        for (int j = 0; j < d; ++j)
            s += expf(clogit[(size_t)(beg + j) * 4 + t] - m);
        m4[t] = m;
        den4[t] = s;
    }
    __syncthreads();
    int head = t / 50;               // (t*4)/200
    float4 acc = {0.f, 0.f, 0.f, 0.f};
    for (int j0 = 0; j0 < d; j0 += 64) {
        int nc = min(64, d - j0);
        if (t < nc * 4) {
            int j = t >> 2, h = t & 3;
            alpha[j][h] = expf(clogit[(size_t)(beg + j0 + j) * 4 + h] - m4[h]) / den4[h];
            if (h == 0) tsl[j] = tlist[beg + j0 + j];
        }
        __syncthreads();
        if (t < 200) {
            for (int j = 0; j < nc; ++j) {
                float a = alpha[j][head];
                ushort4 hv = *(const ushort4*)(h_src + (size_t)tsl[j] * HID + t * 4);
                acc.x += a * bf2f(hv.x);
                acc.y += a * bf2f(hv.y);
                acc.z += a * bf2f(hv.z);
                acc.w += a * bf2f(hv.w);
            }
        }
        __syncthreads();
    }
    if (t < 200) {
        float4 bv = *(const float4*)(bias + t * 4);
        float4 o = {acc.x + bv.x, acc.y + bv.y, acc.z + bv.z, acc.w + bv.w};
        *(float4*)(refined + (size_t)b * HID + t * 4) = o;
    }
}

// DistMult scoring: one wave per triple, float4 loads
__global__ __launch_bounds__(256) void k_score(const int* src_ids, const int* rel_ids,
                                               const int* dst_ids, const int* slot_of_node,
                                               const float* rel_emb, const float* refined,
                                               float* out) {
    int gid = blockIdx.x * 256 + threadIdx.x;
    int b = gid >> 6;
    int lane = threadIdx.x & 63;
    if (b >= BB) return;
    int ss = slot_of_node[src_ids[b]];
    int ds = slot_of_node[dst_ids[b]];
    int r = rel_ids[b];
    const float* sv = refined + (size_t)ss * HID;
    const float* dv = refined + (size_t)ds * HID;
    const float* rv = rel_emb + (size_t)r * HID;
    float acc = 0.f;
    for (int c4 = lane; c4 < 200; c4 += 64) {
        float4 s = *(const float4*)(sv + c4 * 4);
        float4 dq = *(const float4*)(dv + c4 * 4);
        float4 rr = *(const float4*)(rv + c4 * 4);
        acc += s.x * rr.x * dq.x + s.y * rr.y * dq.y + s.z * rr.z * dq.z + s.w * rr.w * dq.w;
    }
    for (int off = 32; off; off >>= 1) acc += __shfl_down(acc, off, 64);
    if (lane == 0) out[b] = acc;
}

extern "C" void kernel_launch(void* const* d_in, const int* in_sizes, int n_in,
                              void* d_out, int out_size, void* d_ws, size_t ws_size,
                              hipStream_t stream) {
    const float* node_emb = (const float*)d_in[0];
    const float* W        = (const float*)d_in[1];
    const float* bias     = (const float*)d_in[2];
    const float* a_src    = (const float*)d_in[3];
    const float* a_dst    = (const float*)d_in[4];
    const float* a_rel    = (const float*)d_in[5];
    const float* rel_feat = (const float*)d_in[6];
    const float* rel_emb  = (const float*)d_in[7];
    const int* edge_index = (const int*)d_in[8];
    const int* edge_type  = (const int*)d_in[9];
    const int* src_ids    = (const int*)d_in[10];
    const int* rel_ids    = (const int*)d_in[11];
    const int* dst_ids    = (const int*)d_in[12];
    float* out = (float*)d_out;

    char* w = (char*)d_ws;
    auto alloc = [&](size_t bytes) -> void* {
        void* p = (void*)w;
        w += (bytes + 255) & ~(size_t)255;
        return p;
    };
    int* slot_of_node = (int*)alloc((size_t)NN * 4);
    int* xrow_of_node = (int*)alloc((size_t)NN * 4);
    int* scorelist    = (int*)alloc((size_t)SLOT_CAP * 4);
    int* rows         = (int*)alloc((size_t)NN * 4);
    int* counters     = (int*)alloc(256);
    int* deg          = (int*)alloc((size_t)SLOT_CAP * 4);
    int* base         = (int*)alloc((size_t)SLOT_CAP * 4);
    int* cursor       = (int*)alloc((size_t)SLOT_CAP * 4);
    int* tlist        = (int*)alloc((size_t)EE * 4);
    float* clogit = (float*)alloc((size_t)EE * 4 * 4);
    float* sS     = (float*)alloc((size_t)SRC_CAP * 4 * 4);
    float* sD     = (float*)alloc((size_t)SRC_CAP * 4 * 4);
    float* Wa     = (float*)alloc((size_t)IN_DIM * 8 * 4);
    float* prel   = (float*)alloc((size_t)NUM_REL * 4 * 4);
    unsigned short* Wt    = (unsigned short*)alloc((size_t)WT_COLS * IN_DIM * 2);
    unsigned short* h_src = (unsigned short*)alloc((size_t)SRC_CAP * HID * 2);
    float* refined = (float*)alloc((size_t)SLOT_CAP * HID * 4);

    int wa_blocks = (IN_DIM * 8 + NUM_REL * HEADS + 3) / 4;
    k_init_wa<<<INIT_BLOCKS + wa_blocks, 256, 0, stream>>>(
        slot_of_node, xrow_of_node, deg, counters,
        W, a_src, a_dst, a_rel, rel_feat, Wa, prel);
    k_build_slots<<<(2 * BB + 255) / 256, 256, 0, stream>>>(src_ids, dst_ids, slot_of_node,
                                                            counters, scorelist);
    k_edge0<<<(EE + 255) / 256, 256, 0, stream>>>(edge_index, slot_of_node,
                                                  xrow_of_node, counters, rows, deg);
    k_tail_scan_wt<<<65 + 224, 256, 0, stream>>>(scorelist, xrow_of_node, counters,
                                                 rows, deg, base, cursor, W, Wa, Wt);
    dim3 ggrid(7, 392);
    k_hgemm<<<ggrid, 256, 0, stream>>>(node_emb, rows, Wt, counters, h_src, sS, sD);
    k_place<<<(EE + 255) / 256, 256, 0, stream>>>(edge_index, edge_type, slot_of_node,
                                                  xrow_of_node, cursor, sS, sD, prel,
                                                  clogit, tlist);
    k_aggregate<<<SLOT_CAP, 256, 0, stream>>>(counters, base, deg, tlist,
                                              clogit, h_src, bias, refined);
    k_score<<<(BB * 64 + 255) / 256, 256, 0, stream>>>(src_ids, rel_ids, dst_ids,
                                                       slot_of_node, rel_emb, refined, out);
}

// Round 4
// 492.132 us; speedup vs baseline: 1.0263x; 1.0263x over previous
//
#include <hip/hip_runtime.h>
#include <hip/hip_bf16.h>
#include <math.h>

#define NN 50000
#define IN_DIM 1024
#define EE 100000
#define NUM_REL 40
#define HEADS 4
#define OUT_D 200
#define HID 800
#define BB 8192
#define SLOT_CAP 16384
#define SRC_CAP 50176   // max gathered rows (>= NN rounded to tile)
#define WT_COLS 896     // 800 W cols + 8 Wa cols + pad

typedef __attribute__((ext_vector_type(8))) short short8;
typedef __attribute__((ext_vector_type(4))) float f32x4;

__device__ inline unsigned short f2bf(float f) {
    unsigned int u = __float_as_uint(f);
    u += 0x7FFF + ((u >> 16) & 1);
    return (unsigned short)(u >> 16);
}
__device__ inline float bf2f(unsigned short s) {
    return __uint_as_float(((unsigned int)s) << 16);
}
__device__ inline void gl2lds16(const unsigned short* g, unsigned short* l) {
    __builtin_amdgcn_global_load_lds(
        (const __attribute__((address_space(1))) void*)g,
        (__attribute__((address_space(3))) void*)l, 16, 0, 0);
}
// packed f32x2 -> bf16x2 (RNE, matches f2bf) ; no builtin on gfx950
__device__ inline short8 cvt8(float4 u, float4 v) {
    union { unsigned int w[4]; short8 s; } r;
    asm("v_cvt_pk_bf16_f32 %0, %1, %2" : "=v"(r.w[0]) : "v"(u.x), "v"(u.y));
    asm("v_cvt_pk_bf16_f32 %0, %1, %2" : "=v"(r.w[1]) : "v"(u.z), "v"(u.w));
    asm("v_cvt_pk_bf16_f32 %0, %1, %2" : "=v"(r.w[2]) : "v"(v.x), "v"(v.y));
    asm("v_cvt_pk_bf16_f32 %0, %1, %2" : "=v"(r.w[3]) : "v"(v.z), "v"(v.w));
    return r.s;
}

// wave-aggregated compaction: one atomicAdd per wave instead of per winner.
__device__ inline int wave_compact(bool won, int* ctr) {
    unsigned long long m = __ballot(won);
    if (!m) return -1;
    int lane = threadIdx.x & 63;
    int leader = __ffsll((long long)m) - 1;
    int base = 0;
    if (lane == leader) base = atomicAdd(ctr, __popcll(m));
    base = __shfl(base, leader, 64);
    return won ? base + __popcll(m & ((1ull << lane) - 1)) : -1;
}

// ---------------- fused: init (blocks 0..195) | Wa/prel (blocks 196..) ----------------
#define INIT_BLOCKS 196
__global__ __launch_bounds__(256) void k_init_wa(int* slot_of_node, int* xrow_of_node,
                                                 int* deg, int* counters,
                                                 const float* W, const float* a_src,
                                                 const float* a_dst, const float* a_rel,
                                                 const float* rel_feat, float* Wa, float* prel) {
    int b = blockIdx.x;
    if (b < INIT_BLOCKS) {
        int i = b * 256 + threadIdx.x;
        if (i < NN) { slot_of_node[i] = -1; xrow_of_node[i] = -1; }
        if (i < SLOT_CAP) deg[i] = 0;
        if (i < 8) counters[i] = 0;
        return;
    }
    int wid = (b - INIT_BLOCKS) * 4 + (threadIdx.x >> 6);
    int lane = threadIdx.x & 63;
    if (wid >= IN_DIM * 8 + NUM_REL * HEADS) return;
    float acc = 0.f;
    int d = lane * 4;
    if (d < OUT_D) {
        const float* row;
        const float* a;
        if (wid < IN_DIM * 8) {
            int k = wid >> 3, c = wid & 7;
            int h = c & 3;
            row = W + (size_t)k * HID + h * OUT_D;
            a = ((c < 4) ? a_src : a_dst) + h * OUT_D;
        } else {
            int j = wid - IN_DIM * 8;
            int r = j >> 2, h = j & 3;
            row = rel_feat + (size_t)r * HID + h * OUT_D;
            a = a_rel + h * OUT_D;
        }
        float4 wv = *(const float4*)(row + d);
        float4 av = *(const float4*)(a + d);
        acc = wv.x * av.x + wv.y * av.y + wv.z * av.z + wv.w * av.w;
    }
    for (int off = 32; off; off >>= 1) acc += __shfl_down(acc, off, 64);
    if (lane == 0) {
        if (wid < IN_DIM * 8) Wa[wid] = acc;
        else prel[wid - IN_DIM * 8] = acc;
    }
}

// compact score nodes (src_ids ∪ dst_ids) -> slots; record unique score list
__global__ void k_build_slots(const int* src_ids, const int* dst_ids,
                              int* slot_of_node, int* counters, int* scorelist) {
    int i = blockIdx.x * 256 + threadIdx.x;
    bool valid = i < 2 * BB;
    int n = 0;
    bool won = false;
    if (valid) {
        n = (i < BB) ? src_ids[i] : dst_ids[i - BB];
        if (slot_of_node[n] == -1)
            won = (atomicCAS(&slot_of_node[n], -1, -2) == -1);
    }
    int s = wave_compact(won, &counters[0]);
    if (won) {
        slot_of_node[n] = s;
        scorelist[s] = n;
    }
}

// survivor pass: compact srcs of surviving edges (xrows 0..nsrc), per-slot degree
__global__ void k_edge0(const int* ei, const int* slot_of_node,
                        int* xrow_of_node, int* counters, int* rows, int* deg) {
    int e = blockIdx.x * 256 + threadIdx.x;
    bool valid = e < EE;
    int slot = -1, sn = 0;
    if (valid) {
        int dn = ei[EE + e];
        slot = slot_of_node[dn];
    }
    bool surv = valid && slot >= 0;
    bool won = false;
    if (surv) {
        sn = ei[e];
        if (xrow_of_node[sn] == -1)
            won = (atomicCAS(&xrow_of_node[sn], -1, -2) == -1);
    }
    int t = wave_compact(won, &counters[1]);
    if (won) {
        rows[t] = sn;
        xrow_of_node[sn] = t;
    }
    if (surv) atomicAdd(&deg[slot], 1);
}

// fused: scan (block 0) | tail (blocks 1..64) | Wt transpose+cast (blocks 65..288)
__global__ __launch_bounds__(256) void k_tail_scan_wt(const int* scorelist, int* xrow_of_node,
                                                      int* counters, int* rows,
                                                      const int* deg, int* base, int* cursor,
                                                      const float* W, const float* Wa,
                                                      unsigned short* Wt) {
    int t = threadIdx.x;
    if (blockIdx.x == 0) {
        __shared__ int pref[257];
        int s = 0;
        const int4* dv = (const int4*)(deg + t * (SLOT_CAP / 256));
        for (int i = 0; i < SLOT_CAP / 256 / 4; ++i) {
            int4 v = dv[i];
            s += v.x + v.y + v.z + v.w;
        }
        pref[t + 1] = s;
        if (t == 0) pref[0] = 0;
        __syncthreads();
        if (t == 0)
            for (int i = 1; i <= 256; ++i) pref[i] += pref[i - 1];
        __syncthreads();
        int r = pref[t];
        for (int i = 0; i < SLOT_CAP / 256; ++i) {
            int idx = t * (SLOT_CAP / 256) + i;
            base[idx] = r;
            cursor[idx] = r;
            r += deg[idx];
        }
        return;
    }
    if (blockIdx.x <= 64) {
        int i = (blockIdx.x - 1) * 256 + t;
        bool valid = i < counters[0];
        int n = 0;
        bool won = false;
        if (valid) {
            n = scorelist[i];
            won = (xrow_of_node[n] < 0);
        }
        int tt = wave_compact(won, &counters[3]);
        if (won) {
            int xr = counters[1] + tt;   // counters[1] stable: edge0 completed
            xrow_of_node[n] = xr;
            rows[xr] = n;
        }
        return;
    }
    // Wt transpose: W[k][c] (f32) -> Wt[c][k] (bf16), cols 800..807 = Wa
    __shared__ float tile[64][65];
    int b = blockIdx.x - 65;                 // 0..223 = 16 k-blocks x 14 col-blocks
    int k0 = (b & 15) * 64, c0 = (b >> 4) * 64;
    {
        int kk = t >> 2, cc = (t & 3) * 16;
        for (int i = 0; i < 16; ++i) {
            int c = c0 + cc + i;
            float v = 0.f;
            if (c < HID) v = W[(size_t)(k0 + kk) * HID + c];
            else if (c < HID + 8) v = Wa[(size_t)(k0 + kk) * 8 + (c - HID)];
            tile[cc + i][kk] = v;
        }
    }
    __syncthreads();
    {
        int cc = t >> 2, kk = (t & 3) * 16;
        unsigned short o[16];
        for (int i = 0; i < 16; ++i) o[i] = f2bf(tile[cc][kk + i]);
        *(short8*)(Wt + (size_t)(c0 + cc) * IN_DIM + k0 + kk) = *(short8*)o;
        *(short8*)(Wt + (size_t)(c0 + cc) * IN_DIM + k0 + kk + 8) = *(short8*)(o + 8);
    }
}

// MFMA bf16 GEMM with fused gather+cast, latency-oriented schedule.
// 128x128 tile, 256 threads (4 waves, 64x64 each), BK=32, double-buffered
// LDS = 32 KB -> 3 blocks/CU (launch_bounds 256,3). Per K-step (ONE barrier):
//   prefetch next tile {A: 4x float4 global->reg; B: 2x global_load_lds}
//   compute current {8x ds_read_b128 + 16 MFMA, setprio-wrapped}
//   cvt_pk next A -> ds_write_b128 (load latency hidden under compute)
//   vmcnt(0)+lgkmcnt(0)+s_barrier (loads issued a full compute-phase ago)
// Fragment-ordered LDS chunks (stage-thread id = read chunk id): conflict-free.
// XCD swizzle: 2744 blocks = 49 groups of 56; XCD x sweeps row-panel g*8+x
// across its 7 col-tiles back-to-back (A panel 512 KB stays in its L2).
#define GBM 128
#define GBN 128
#define GBK 32

#define ALOADR(K) do {                                                  \
    const float* p0 = ax0 + (size_t)(K) * 32;                           \
    const float* p1 = ax1 + (size_t)(K) * 32;                           \
    av0 = *(const float4*)(p0);                                         \
    av1 = *(const float4*)(p0 + 4);                                     \
    av2 = *(const float4*)(p1);                                         \
    av3 = *(const float4*)(p1 + 4);                                     \
} while (0)

#define AWRITE(AS) do {                                                 \
    short8 s0 = cvt8(av0, av1);                                         \
    short8 s1 = cvt8(av2, av3);                                         \
    *(short8*)&(AS)[(size_t)t * 8] = s0;                                \
    *(short8*)&(AS)[(size_t)(256 + t) * 8] = s1;                        \
} while (0)

#define BSTAGE(BS, K) do {                                              \
    gl2lds16(bP0 + (size_t)(K) * 32, (BS) + (size_t)t * 8);             \
    gl2lds16(bP1 + (size_t)(K) * 32, (BS) + (size_t)(256 + t) * 8);     \
} while (0)

#define COMPUTE(AS, BS) do {                                            \
    short8 af[4], bf4[4];                                               \
    _Pragma("unroll")                                                   \
    for (int i = 0; i < 4; ++i)                                         \
        af[i] = *(const short8*)&(AS)[(size_t)((ga + i) * 64 + lane) * 8]; \
    _Pragma("unroll")                                                   \
    for (int j = 0; j < 4; ++j)                                         \
        bf4[j] = *(const short8*)&(BS)[(size_t)((gb + j) * 64 + lane) * 8]; \
    __builtin_amdgcn_s_setprio(1);                                      \
    _Pragma("unroll")                                                   \
    for (int i = 0; i < 4; ++i)                                         \
        _Pragma("unroll")                                               \
        for (int j = 0; j < 4; ++j)                                     \
            acc[i][j] = __builtin_amdgcn_mfma_f32_16x16x32_bf16(af[i], bf4[j], acc[i][j], 0, 0, 0); \
    __builtin_amdgcn_s_setprio(0);                                      \
} while (0)

#define GATE asm volatile("s_waitcnt vmcnt(0) lgkmcnt(0)\n\ts_barrier" ::: "memory")

__global__ __launch_bounds__(256, 3) void k_hgemm(const float* x, const int* rows,
                                                  const unsigned short* Wt,
                                                  const int* counters, unsigned short* h_src,
                                                  float* sS, float* sD) {
    int nsrc = counters[1];
    int nneed = nsrc + counters[3];
    int lin = blockIdx.x + 7 * blockIdx.y;   // 0..2743 = 49 groups of 56
    int g = lin / 56, r = lin % 56;
    int rowb = g * 8 + (r & 7);              // 0..391
    int colb = r >> 3;                       // 0..6
    int col0 = colb * GBN;
    int row0 = rowb * GBM;
    int rowlim = (col0 == 768) ? nneed : nsrc;
    if (row0 >= rowlim) return;
    __shared__ unsigned short As0[GBM * GBK];  // 8 KB each
    __shared__ unsigned short As1[GBM * GBK];
    __shared__ unsigned short Bs0[GBN * GBK];
    __shared__ unsigned short Bs1[GBN * GBK];
    int t = threadIdx.x;
    int r0 = ((t >> 6) << 4) + (t & 15);     // 0..63
    int ko = ((t >> 4) & 3) << 3;            // 0,8,16,24
    // A-path: gathered node rows (clamped for partially-active tiles)
    int lim = nneed - 1;
    int n0 = rows[min(row0 + r0, lim)];
    int n1 = rows[min(row0 + r0 + 64, lim)];
    const float* ax0 = x + (size_t)n0 * IN_DIM + ko;
    const float* ax1 = x + (size_t)n1 * IN_DIM + ko;
    const unsigned short* bP0 = Wt + (size_t)(col0 + r0) * IN_DIM + ko;
    const unsigned short* bP1 = bP0 + (size_t)64 * IN_DIM;
    int w = t >> 6, lane = t & 63;
    int ga = (w >> 1) * 4, gb = (w & 1) * 4;
    int wr = (w >> 1) * 64, wc = (w & 1) * 64;
    int fm = lane & 15, fq = lane >> 4;
    float4 av0, av1, av2, av3;
    f32x4 acc[4][4] = {};
    // prologue: tile 0
    ALOADR(0);
    BSTAGE(Bs0, 0);
    AWRITE(As0);
    GATE;
#pragma unroll 1
    for (int k = 0; k < 32; k += 2) {
        ALOADR(k + 1);
        BSTAGE(Bs1, k + 1);
        COMPUTE(As0, Bs0);
        AWRITE(As1);
        GATE;
        if (k < 30) {
            ALOADR(k + 2);
            BSTAGE(Bs0, k + 2);
        }
        COMPUTE(As1, Bs1);
        if (k < 30) {
            AWRITE(As0);
            GATE;
        }
    }
#pragma unroll
    for (int i = 0; i < 4; ++i) {
#pragma unroll
        for (int j = 0; j < 4; ++j) {
            int gcol = col0 + wc + j * 16 + fm;
            if (gcol >= HID + 8) continue;
#pragma unroll
            for (int rr = 0; rr < 4; ++rr) {
                int grow = row0 + wr + i * 16 + fq * 4 + rr;
                float v = acc[i][j][rr];
                if (gcol < HID) {
                    if (grow < nsrc) h_src[(size_t)grow * HID + gcol] = f2bf(v);
                } else if (grow < nneed) {
                    int c = gcol - HID;
                    if (c < 4) sS[grow * 4 + c] = v;
                    else sD[grow * 4 + (c - 4)] = v;
                }
            }
        }
    }
}

// place surviving edges into CSR, computing logits at final position
__global__ void k_place(const int* ei, const int* etype, const int* slot_of_node,
                        const int* xrow_of_node, int* cursor,
                        const float* sS, const float* sD, const float* prel,
                        float* clogit, int* tlist) {
    int e = blockIdx.x * 256 + threadIdx.x;
    if (e >= EE) return;
    int dn = ei[EE + e];
    int slot = slot_of_node[dn];
    if (slot < 0) return;
    int sn = ei[e];
    int r = etype[e];
    int xs = xrow_of_node[sn];
    int xd = xrow_of_node[dn];
    int pos = atomicAdd(&cursor[slot], 1);
    tlist[pos] = xs;
    float4 lg;
    float* lp = (float*)&lg;
#pragma unroll
    for (int h = 0; h < 4; ++h) {
        float v = sS[xs * 4 + h] + sD[xd * 4 + h] + prel[r * 4 + h];
        lp[h] = v > 0.f ? v : 0.2f * v;
    }
    *(float4*)&clogit[(size_t)pos * 4] = lg;
}

// per-dst-slot softmax + aggregate: one block per slot; 200 lanes x 4 elems,
// ushort4 (8B) h_src loads
__global__ __launch_bounds__(256) void k_aggregate(const int* counters, const int* base,
                                                   const int* deg, const int* tlist,
                                                   const float* clogit,
                                                   const unsigned short* h_src, const float* bias,
                                                   float* refined) {
    int b = blockIdx.x;
    if (b >= counters[0]) return;
    int beg = base[b], d = deg[b];
    __shared__ float m4[4], den4[4];
    __shared__ float alpha[64][4];
    __shared__ int tsl[64];
    int t = threadIdx.x;
    if (t < 4) {
        float m = -3e38f;
        for (int j = 0; j < d; ++j)
            m = fmaxf(m, clogit[(size_t)(beg + j) * 4 + t]);
        float s = 0.f;
        for (int j = 0; j < d; ++j)
            s += expf(clogit[(size_t)(beg + j) * 4 + t] - m);
        m4[t] = m;
        den4[t] = s;
    }
    __syncthreads();
    int head = t / 50;               // (t*4)/200
    float4 acc = {0.f, 0.f, 0.f, 0.f};
    for (int j0 = 0; j0 < d; j0 += 64) {
        int nc = min(64, d - j0);
        if (t < nc * 4) {
            int j = t >> 2, h = t & 3;
            alpha[j][h] = expf(clogit[(size_t)(beg + j0 + j) * 4 + h] - m4[h]) / den4[h];
            if (h == 0) tsl[j] = tlist[beg + j0 + j];
        }
        __syncthreads();
        if (t < 200) {
            for (int j = 0; j < nc; ++j) {
                float a = alpha[j][head];
                ushort4 hv = *(const ushort4*)(h_src + (size_t)tsl[j] * HID + t * 4);
                acc.x += a * bf2f(hv.x);
                acc.y += a * bf2f(hv.y);
                acc.z += a * bf2f(hv.z);
                acc.w += a * bf2f(hv.w);
            }
        }
        __syncthreads();
    }
    if (t < 200) {
        float4 bv = *(const float4*)(bias + t * 4);
        float4 o = {acc.x + bv.x, acc.y + bv.y, acc.z + bv.z, acc.w + bv.w};
        *(float4*)(refined + (size_t)b * HID + t * 4) = o;
    }
}

// DistMult scoring: one wave per triple, float4 loads
__global__ __launch_bounds__(256) void k_score(const int* src_ids, const int* rel_ids,
                                               const int* dst_ids, const int* slot_of_node,
                                               const float* rel_emb, const float* refined,
                                               float* out) {
    int gid = blockIdx.x * 256 + threadIdx.x;
    int b = gid >> 6;
    int lane = threadIdx.x & 63;
    if (b >= BB) return;
    int ss = slot_of_node[src_ids[b]];
    int ds = slot_of_node[dst_ids[b]];
    int r = rel_ids[b];
    const float* sv = refined + (size_t)ss * HID;
    const float* dv = refined + (size_t)ds * HID;
    const float* rv = rel_emb + (size_t)r * HID;
    float acc = 0.f;
    for (int c4 = lane; c4 < 200; c4 += 64) {
        float4 s = *(const float4*)(sv + c4 * 4);
        float4 dq = *(const float4*)(dv + c4 * 4);
        float4 rr = *(const float4*)(rv + c4 * 4);
        acc += s.x * rr.x * dq.x + s.y * rr.y * dq.y + s.z * rr.z * dq.z + s.w * rr.w * dq.w;
    }
    for (int off = 32; off; off >>= 1) acc += __shfl_down(acc, off, 64);
    if (lane == 0) out[b] = acc;
}

extern "C" void kernel_launch(void* const* d_in, const int* in_sizes, int n_in,
                              void* d_out, int out_size, void* d_ws, size_t ws_size,
                              hipStream_t stream) {
    const float* node_emb = (const float*)d_in[0];
    const float* W        = (const float*)d_in[1];
    const float* bias     = (const float*)d_in[2];
    const float* a_src    = (const float*)d_in[3];
    const float* a_dst    = (const float*)d_in[4];
    const float* a_rel    = (const float*)d_in[5];
    const float* rel_feat = (const float*)d_in[6];
    const float* rel_emb  = (const float*)d_in[7];
    const int* edge_index = (const int*)d_in[8];
    const int* edge_type  = (const int*)d_in[9];
    const int* src_ids    = (const int*)d_in[10];
    const int* rel_ids    = (const int*)d_in[11];
    const int* dst_ids    = (const int*)d_in[12];
    float* out = (float*)d_out;

    char* w = (char*)d_ws;
    auto alloc = [&](size_t bytes) -> void* {
        void* p = (void*)w;
        w += (bytes + 255) & ~(size_t)255;
        return p;
    };
    int* slot_of_node = (int*)alloc((size_t)NN * 4);
    int* xrow_of_node = (int*)alloc((size_t)NN * 4);
    int* scorelist    = (int*)alloc((size_t)SLOT_CAP * 4);
    int* rows         = (int*)alloc((size_t)NN * 4);
    int* counters     = (int*)alloc(256);
    int* deg          = (int*)alloc((size_t)SLOT_CAP * 4);
    int* base         = (int*)alloc((size_t)SLOT_CAP * 4);
    int* cursor       = (int*)alloc((size_t)SLOT_CAP * 4);
    int* tlist        = (int*)alloc((size_t)EE * 4);
    float* clogit = (float*)alloc((size_t)EE * 4 * 4);
    float* sS     = (float*)alloc((size_t)SRC_CAP * 4 * 4);
    float* sD     = (float*)alloc((size_t)SRC_CAP * 4 * 4);
    float* Wa     = (float*)alloc((size_t)IN_DIM * 8 * 4);
    float* prel   = (float*)alloc((size_t)NUM_REL * 4 * 4);
    unsigned short* Wt    = (unsigned short*)alloc((size_t)WT_COLS * IN_DIM * 2);
    unsigned short* h_src = (unsigned short*)alloc((size_t)SRC_CAP * HID * 2);
    float* refined = (float*)alloc((size_t)SLOT_CAP * HID * 4);

    int wa_blocks = (IN_DIM * 8 + NUM_REL * HEADS + 3) / 4;
    k_init_wa<<<INIT_BLOCKS + wa_blocks, 256, 0, stream>>>(
        slot_of_node, xrow_of_node, deg, counters,
        W, a_src, a_dst, a_rel, rel_feat, Wa, prel);
    k_build_slots<<<(2 * BB + 255) / 256, 256, 0, stream>>>(src_ids, dst_ids, slot_of_node,
                                                            counters, scorelist);
    k_edge0<<<(EE + 255) / 256, 256, 0, stream>>>(edge_index, slot_of_node,
                                                  xrow_of_node, counters, rows, deg);
    k_tail_scan_wt<<<65 + 224, 256, 0, stream>>>(scorelist, xrow_of_node, counters,
                                                 rows, deg, base, cursor, W, Wa, Wt);
    dim3 ggrid(7, 392);
    k_hgemm<<<ggrid, 256, 0, stream>>>(node_emb, rows, Wt, counters, h_src, sS, sD);
    k_place<<<(EE + 255) / 256, 256, 0, stream>>>(edge_index, edge_type, slot_of_node,
                                                  xrow_of_node, cursor, sS, sD, prel,
                                                  clogit, tlist);
    k_aggregate<<<SLOT_CAP, 256, 0, stream>>>(counters, base, deg, tlist,
                                              clogit, h_src, bias, refined);
    k_score<<<(BB * 64 + 255) / 256, 256, 0, stream>>>(src_ids, rel_ids, dst_ids,
                                                       slot_of_node, rel_emb, refined, out);
}

// Round 5
// 461.033 us; speedup vs baseline: 1.0956x; 1.0675x over previous
//
#include <hip/hip_runtime.h>
#include <hip/hip_bf16.h>
#include <math.h>

#define NN 50000
#define IN_DIM 1024
#define EE 100000
#define NUM_REL 40
#define HEADS 4
#define OUT_D 200
#define HID 800
#define BB 8192
#define SLOT_CAP 16384
#define SRC_CAP 50176   // max gathered rows (>= NN rounded to tile)

typedef __attribute__((ext_vector_type(8))) short short8;
typedef __attribute__((ext_vector_type(4))) float f32x4;
typedef __attribute__((ext_vector_type(2))) unsigned int u32x2;

__device__ inline unsigned short f2bf(float f) {
    unsigned int u = __float_as_uint(f);
    u += 0x7FFF + ((u >> 16) & 1);
    return (unsigned short)(u >> 16);
}
__device__ inline float bf2f(unsigned short s) {
    return __uint_as_float(((unsigned int)s) << 16);
}
__device__ inline void gl2lds16(const unsigned short* g, unsigned short* l) {
    __builtin_amdgcn_global_load_lds(
        (const __attribute__((address_space(1))) void*)g,
        (__attribute__((address_space(3))) void*)l, 16, 0, 0);
}
// packed f32x4 -> 4 bf16 (RNE, matches f2bf); no builtin on gfx950
__device__ inline u32x2 cvt4(float4 v) {
    u32x2 r;
    asm("v_cvt_pk_bf16_f32 %0, %1, %2" : "=v"(r.x) : "v"(v.x), "v"(v.y));
    asm("v_cvt_pk_bf16_f32 %0, %1, %2" : "=v"(r.y) : "v"(v.z), "v"(v.w));
    return r;
}

// wave-aggregated compaction: one atomicAdd per wave instead of per winner.
__device__ inline int wave_compact(bool won, int* ctr) {
    unsigned long long m = __ballot(won);
    if (!m) return -1;
    int lane = threadIdx.x & 63;
    int leader = __ffsll((long long)m) - 1;
    int base = 0;
    if (lane == leader) base = atomicAdd(ctr, __popcll(m));
    base = __shfl(base, leader, 64);
    return won ? base + __popcll(m & ((1ull << lane) - 1)) : -1;
}

// ---------------- fused: init (blocks 0..195) | Wa/prel (blocks 196..) ----------------
#define INIT_BLOCKS 196
__global__ __launch_bounds__(256) void k_init_wa(int* slot_of_node, int* xrow_of_node,
                                                 int* deg, int* counters,
                                                 const float* W, const float* a_src,
                                                 const float* a_dst, const float* a_rel,
                                                 const float* rel_feat, float* Wa, float* prel) {
    int b = blockIdx.x;
    if (b < INIT_BLOCKS) {
        int i = b * 256 + threadIdx.x;
        if (i < NN) { slot_of_node[i] = -1; xrow_of_node[i] = -1; }
        if (i < SLOT_CAP) deg[i] = 0;
        if (i < 8) counters[i] = 0;
        return;
    }
    int wid = (b - INIT_BLOCKS) * 4 + (threadIdx.x >> 6);
    int lane = threadIdx.x & 63;
    if (wid >= IN_DIM * 8 + NUM_REL * HEADS) return;
    float acc = 0.f;
    int d = lane * 4;
    if (d < OUT_D) {
        const float* row;
        const float* a;
        if (wid < IN_DIM * 8) {
            int k = wid >> 3, c = wid & 7;
            int h = c & 3;
            row = W + (size_t)k * HID + h * OUT_D;
            a = ((c < 4) ? a_src : a_dst) + h * OUT_D;
        } else {
            int j = wid - IN_DIM * 8;
            int r = j >> 2, h = j & 3;
            row = rel_feat + (size_t)r * HID + h * OUT_D;
            a = a_rel + h * OUT_D;
        }
        float4 wv = *(const float4*)(row + d);
        float4 av = *(const float4*)(a + d);
        acc = wv.x * av.x + wv.y * av.y + wv.z * av.z + wv.w * av.w;
    }
    for (int off = 32; off; off >>= 1) acc += __shfl_down(acc, off, 64);
    if (lane == 0) {
        if (wid < IN_DIM * 8) Wa[wid] = acc;
        else prel[wid - IN_DIM * 8] = acc;
    }
}

// compact score nodes (src_ids ∪ dst_ids) -> slots; record unique score list
__global__ void k_build_slots(const int* src_ids, const int* dst_ids,
                              int* slot_of_node, int* counters, int* scorelist) {
    int i = blockIdx.x * 256 + threadIdx.x;
    bool valid = i < 2 * BB;
    int n = 0;
    bool won = false;
    if (valid) {
        n = (i < BB) ? src_ids[i] : dst_ids[i - BB];
        if (slot_of_node[n] == -1)
            won = (atomicCAS(&slot_of_node[n], -1, -2) == -1);
    }
    int s = wave_compact(won, &counters[0]);
    if (won) {
        slot_of_node[n] = s;
        scorelist[s] = n;
    }
}

// survivor pass: compact srcs of surviving edges (xrows 0..nsrc), per-slot degree
__global__ void k_edge0(const int* ei, const int* slot_of_node,
                        int* xrow_of_node, int* counters, int* rows, int* deg) {
    int e = blockIdx.x * 256 + threadIdx.x;
    bool valid = e < EE;
    int slot = -1, sn = 0;
    if (valid) {
        int dn = ei[EE + e];
        slot = slot_of_node[dn];
    }
    bool surv = valid && slot >= 0;
    bool won = false;
    if (surv) {
        sn = ei[e];
        if (xrow_of_node[sn] == -1)
            won = (atomicCAS(&xrow_of_node[sn], -1, -2) == -1);
    }
    int t = wave_compact(won, &counters[1]);
    if (won) {
        rows[t] = sn;
        xrow_of_node[sn] = t;
    }
    if (surv) atomicAdd(&deg[slot], 1);
}

// fused: scan (block 0) | tail (blocks 1..64) | Wt fragment-chunk pack (65..288)
// Wt layout: for coltile n0 (0..6), kstep ks (0..31): 512 chunks of 8 bf16,
// chunk c -> col = (c>>6)*16 + (c&15), kc = (c>>4)&3, shorts kj=0..7 hold
// W[ks*32 + kc*8 + kj][n0*128 + col]. This is EXACTLY the LDS fragment order
// the GEMM's global_load_lds consumes -> B staging is fully linear.
__global__ __launch_bounds__(256) void k_tail_scan_wt(const int* scorelist, int* xrow_of_node,
                                                      int* counters, int* rows,
                                                      const int* deg, int* base, int* cursor,
                                                      const float* W, const float* Wa,
                                                      unsigned short* Wt) {
    int t = threadIdx.x;
    if (blockIdx.x == 0) {
        __shared__ int pref[257];
        int s = 0;
        const int4* dv = (const int4*)(deg + t * (SLOT_CAP / 256));
        for (int i = 0; i < SLOT_CAP / 256 / 4; ++i) {
            int4 v = dv[i];
            s += v.x + v.y + v.z + v.w;
        }
        pref[t + 1] = s;
        if (t == 0) pref[0] = 0;
        __syncthreads();
        if (t == 0)
            for (int i = 1; i <= 256; ++i) pref[i] += pref[i - 1];
        __syncthreads();
        int r = pref[t];
        for (int i = 0; i < SLOT_CAP / 256; ++i) {
            int idx = t * (SLOT_CAP / 256) + i;
            base[idx] = r;
            cursor[idx] = r;
            r += deg[idx];
        }
        return;
    }
    if (blockIdx.x <= 64) {
        int i = (blockIdx.x - 1) * 256 + t;
        bool valid = i < counters[0];
        int n = 0;
        bool won = false;
        if (valid) {
            n = scorelist[i];
            won = (xrow_of_node[n] < 0);
        }
        int tt = wave_compact(won, &counters[3]);
        if (won) {
            int xr = counters[1] + tt;   // counters[1] stable: edge0 completed
            xrow_of_node[n] = xr;
            rows[xr] = n;
        }
        return;
    }
    int bw = blockIdx.x - 65;            // 0..223 = 7 coltiles x 32 ksteps
    int n0 = bw >> 5, ks = bw & 31;
    unsigned short* dst = Wt + (size_t)(n0 * 32 + ks) * 512 * 8;
#pragma unroll
    for (int q = 0; q < 2; ++q) {
        int c = q * 256 + t;
        int col = ((c >> 6) << 4) + (c & 15);
        int kc = (c >> 4) & 3;
        int gcol = n0 * 128 + col;
        int kbase = ks * 32 + kc * 8;
        unsigned short o[8];
        if (gcol < HID) {
#pragma unroll
            for (int kj = 0; kj < 8; ++kj) o[kj] = f2bf(W[(size_t)(kbase + kj) * HID + gcol]);
        } else if (gcol < HID + 8) {
#pragma unroll
            for (int kj = 0; kj < 8; ++kj) o[kj] = f2bf(Wa[(size_t)(kbase + kj) * 8 + (gcol - HID)]);
        } else {
#pragma unroll
            for (int kj = 0; kj < 8; ++kj) o[kj] = 0;
        }
        *(short8*)(dst + (size_t)c * 8) = *(short8*)o;
    }
}

// MFMA bf16 GEMM, transaction-minimal + counted-vmcnt depth-2 pipeline.
// 128x128 tile, 256 threads (4 waves, 64x64 each), BK=32.
// A (gather, reg-staged): thread t reads float4 at rows r0+{0,32,64,96},
//   byte-off (t&7)*16 -> each load instr covers 8 FULL 128B row-slices
//   (minimum lines/instr); cvt_pk -> ds_write_b64 into fragment chunks.
// B: global_load_lds from fragment-chunk-linear Wt (sequential 16B/lane).
// Buffers: As x2 (8KB), Bs x3 (8KB) = 40KB LDS. Steady step:
//   BSTAGE(k+2) | COMPUTE(k) | vmcnt(2) [waits B(k+1)+A(k+1), k+2 stays
//   in flight] | AWRITE(k+1) | ALOADR(k+2) | lgkmcnt(0)+barrier.
// Nothing ever waits on a load issued in the same step.
// XCD swizzle: 2744 = 49 groups of 56; XCD x sweeps row-panel g*8+x across
// its 7 col-tiles back-to-back (A panel 512 KB stays in that XCD's L2).
#define GBM 128
#define GBN 128

#define ALOADR(K) do {                                                  \
    avA0 = *(const float4*)(ax0 + (size_t)(K) * 32);                    \
    avA1 = *(const float4*)(ax1 + (size_t)(K) * 32);                    \
    avA2 = *(const float4*)(ax2 + (size_t)(K) * 32);                    \
    avA3 = *(const float4*)(ax3 + (size_t)(K) * 32);                    \
} while (0)

#define AWRITE(AS) do {                                                 \
    *(u32x2*)((AS) + acw)        = cvt4(avA0);                          \
    *(u32x2*)((AS) + acw + 1024) = cvt4(avA1);                          \
    *(u32x2*)((AS) + acw + 2048) = cvt4(avA2);                          \
    *(u32x2*)((AS) + acw + 3072) = cvt4(avA3);                          \
} while (0)

#define BSTAGE(BS, KS) do {                                             \
    gl2lds16(bsrc + ((size_t)(KS) * 512 + t) * 8,       (BS) + (size_t)t * 8);       \
    gl2lds16(bsrc + ((size_t)(KS) * 512 + 256 + t) * 8, (BS) + (size_t)(256 + t) * 8); \
} while (0)

#define COMPUTE(AS, BS) do {                                            \
    short8 af[4], bf4[4];                                               \
    _Pragma("unroll")                                                   \
    for (int i = 0; i < 4; ++i)                                         \
        af[i] = *(const short8*)&(AS)[(size_t)((ga + i) * 64 + lane) * 8]; \
    _Pragma("unroll")                                                   \
    for (int j = 0; j < 4; ++j)                                         \
        bf4[j] = *(const short8*)&(BS)[(size_t)((gb + j) * 64 + lane) * 8]; \
    __builtin_amdgcn_s_setprio(1);                                      \
    _Pragma("unroll")                                                   \
    for (int i = 0; i < 4; ++i)                                         \
        _Pragma("unroll")                                               \
        for (int j = 0; j < 4; ++j)                                     \
            acc[i][j] = __builtin_amdgcn_mfma_f32_16x16x32_bf16(af[i], bf4[j], acc[i][j], 0, 0, 0); \
    __builtin_amdgcn_s_setprio(0);                                      \
} while (0)

#define WAIT2   asm volatile("s_waitcnt vmcnt(2)" ::: "memory")
#define WAIT0   asm volatile("s_waitcnt vmcnt(0)" ::: "memory")
#define PUBBAR  asm volatile("s_waitcnt lgkmcnt(0)\n\ts_barrier" ::: "memory")

__global__ __launch_bounds__(256, 3) void k_hgemm(const float* x, const int* rows,
                                                  const unsigned short* Wt,
                                                  const int* counters, unsigned short* h_src,
                                                  float* sS, float* sD) {
    int nsrc = counters[1];
    int nneed = nsrc + counters[3];
    int lin = blockIdx.x + 7 * blockIdx.y;   // 0..2743 = 49 groups of 56
    int g = lin / 56, r = lin % 56;
    int rowb = g * 8 + (r & 7);              // 0..391
    int colb = r >> 3;                       // 0..6
    int col0 = colb * GBN;
    int row0 = rowb * GBM;
    int rowlim = (colb == 6) ? nneed : nsrc;
    if (row0 >= rowlim) return;
    __shared__ unsigned short As0[4096], As1[4096];            // 8 KB each
    __shared__ unsigned short Bs0[4096], Bs1[4096], Bs2[4096]; // 8 KB each
    int t = threadIdx.x;
    int r0 = t >> 3;                    // 0..31
    int fo = (t & 7) * 4;               // float offset within 32-float K-slice
    int lim = nneed - 1;
    const float* ax0 = x + (size_t)rows[min(row0 + r0,      lim)] * IN_DIM + fo;
    const float* ax1 = x + (size_t)rows[min(row0 + r0 + 32, lim)] * IN_DIM + fo;
    const float* ax2 = x + (size_t)rows[min(row0 + r0 + 64, lim)] * IN_DIM + fo;
    const float* ax3 = x + (size_t)rows[min(row0 + r0 + 96, lim)] * IN_DIM + fo;
    // A LDS chunk addr (shorts): chunk(row,kc) = (row>>4)*64 + kc*16 + (row&15)
    int kc = (t & 7) >> 1, half = t & 1;
    int acw = (((r0 >> 4) * 64) + kc * 16 + (r0 & 15)) * 8 + half * 4;
    const unsigned short* bsrc = Wt + (size_t)colb * 32 * 512 * 8;
    int w = t >> 6, lane = t & 63;
    int ga = (w >> 1) * 4, gb = (w & 1) * 4;
    int wr = (w >> 1) * 64, wc = (w & 1) * 64;
    int fm = lane & 15, fq = lane >> 4;
    float4 avA0, avA1, avA2, avA3;
    f32x4 acc[4][4] = {};
    unsigned short *bA = Bs0, *bB = Bs1, *bC = Bs2;
    unsigned short *aC = As0, *aW = As1;
    // prologue: issue order B0(2), A0(4), B1(2) -> vmcnt(2) = B0+A0 done
    BSTAGE(bA, 0);
    ALOADR(0);
    BSTAGE(bB, 1);
    WAIT2;
    AWRITE(aC);
    ALOADR(1);
    PUBBAR;
#pragma unroll 1
    for (int k = 0; k < 30; ++k) {
        BSTAGE(bC, k + 2);
        COMPUTE(aC, bA);
        WAIT2;                 // B(k+1)+A(k+1) done; B(k+2) stays in flight
        AWRITE(aW);
        ALOADR(k + 2);
        PUBBAR;
        unsigned short* tb = bA; bA = bB; bB = bC; bC = tb;
        unsigned short* ta = aC; aC = aW; aW = ta;
    }
    // k = 30: nothing new to stage
    COMPUTE(aC, bA);
    WAIT0;                     // drain B(31)+A(31)
    AWRITE(aW);
    PUBBAR;
    // k = 31
    COMPUTE(aW, bB);
#pragma unroll
    for (int i = 0; i < 4; ++i) {
#pragma unroll
        for (int j = 0; j < 4; ++j) {
            int gcol = col0 + wc + j * 16 + fm;
            if (gcol >= HID + 8) continue;
#pragma unroll
            for (int rr = 0; rr < 4; ++rr) {
                int grow = row0 + wr + i * 16 + fq * 4 + rr;
                float v = acc[i][j][rr];
                if (gcol < HID) {
                    if (grow < nsrc) h_src[(size_t)grow * HID + gcol] = f2bf(v);
                } else if (grow < nneed) {
                    int c = gcol - HID;
                    if (c < 4) sS[grow * 4 + c] = v;
                    else sD[grow * 4 + (c - 4)] = v;
                }
            }
        }
    }
}

// place surviving edges into CSR, computing logits at final position
__global__ void k_place(const int* ei, const int* etype, const int* slot_of_node,
                        const int* xrow_of_node, int* cursor,
                        const float* sS, const float* sD, const float* prel,
                        float* clogit, int* tlist) {
    int e = blockIdx.x * 256 + threadIdx.x;
    if (e >= EE) return;
    int dn = ei[EE + e];
    int slot = slot_of_node[dn];
    if (slot < 0) return;
    int sn = ei[e];
    int r = etype[e];
    int xs = xrow_of_node[sn];
    int xd = xrow_of_node[dn];
    int pos = atomicAdd(&cursor[slot], 1);
    tlist[pos] = xs;
    float4 lg;
    float* lp = (float*)&lg;
#pragma unroll
    for (int h = 0; h < 4; ++h) {
        float v = sS[xs * 4 + h] + sD[xd * 4 + h] + prel[r * 4 + h];
        lp[h] = v > 0.f ? v : 0.2f * v;
    }
    *(float4*)&clogit[(size_t)pos * 4] = lg;
}

// per-dst-slot softmax + aggregate: one block per slot; 200 lanes x 4 elems,
// ushort4 (8B) h_src loads
__global__ __launch_bounds__(256) void k_aggregate(const int* counters, const int* base,
                                                   const int* deg, const int* tlist,
                                                   const float* clogit,
                                                   const unsigned short* h_src, const float* bias,
                                                   float* refined) {
    int b = blockIdx.x;
    if (b >= counters[0]) return;
    int beg = base[b], d = deg[b];
    __shared__ float m4[4], den4[4];
    __shared__ float alpha[64][4];
    __shared__ int tsl[64];
    int t = threadIdx.x;
    if (t < 4) {
        float m = -3e38f;
        for (int j = 0; j < d; ++j)
            m = fmaxf(m, clogit[(size_t)(beg + j) * 4 + t]);
        float s = 0.f;
        for (int j = 0; j < d; ++j)
            s += expf(clogit[(size_t)(beg + j) * 4 + t] - m);
        m4[t] = m;
        den4[t] = s;
    }
    __syncthreads();
    int head = t / 50;               // (t*4)/200
    float4 acc = {0.f, 0.f, 0.f, 0.f};
    for (int j0 = 0; j0 < d; j0 += 64) {
        int nc = min(64, d - j0);
        if (t < nc * 4) {
            int j = t >> 2, h = t & 3;
            alpha[j][h] = expf(clogit[(size_t)(beg + j0 + j) * 4 + h] - m4[h]) / den4[h];
            if (h == 0) tsl[j] = tlist[beg + j0 + j];
        }
        __syncthreads();
        if (t < 200) {
            for (int j = 0; j < nc; ++j) {
                float a = alpha[j][head];
                ushort4 hv = *(const ushort4*)(h_src + (size_t)tsl[j] * HID + t * 4);
                acc.x += a * bf2f(hv.x);
                acc.y += a * bf2f(hv.y);
                acc.z += a * bf2f(hv.z);
                acc.w += a * bf2f(hv.w);
            }
        }
        __syncthreads();
    }
    if (t < 200) {
        float4 bv = *(const float4*)(bias + t * 4);
        float4 o = {acc.x + bv.x, acc.y + bv.y, acc.z + bv.z, acc.w + bv.w};
        *(float4*)(refined + (size_t)b * HID + t * 4) = o;
    }
}

// DistMult scoring: one wave per triple, float4 loads
__global__ __launch_bounds__(256) void k_score(const int* src_ids, const int* rel_ids,
                                               const int* dst_ids, const int* slot_of_node,
                                               const float* rel_emb, const float* refined,
                                               float* out) {
    int gid = blockIdx.x * 256 + threadIdx.x;
    int b = gid >> 6;
    int lane = threadIdx.x & 63;
    if (b >= BB) return;
    int ss = slot_of_node[src_ids[b]];
    int ds = slot_of_node[dst_ids[b]];
    int r = rel_ids[b];
    const float* sv = refined + (size_t)ss * HID;
    const float* dv = refined + (size_t)ds * HID;
    const float* rv = rel_emb + (size_t)r * HID;
    float acc = 0.f;
    for (int c4 = lane; c4 < 200; c4 += 64) {
        float4 s = *(const float4*)(sv + c4 * 4);
        float4 dq = *(const float4*)(dv + c4 * 4);
        float4 rr = *(const float4*)(rv + c4 * 4);
        acc += s.x * rr.x * dq.x + s.y * rr.y * dq.y + s.z * rr.z * dq.z + s.w * rr.w * dq.w;
    }
    for (int off = 32; off; off >>= 1) acc += __shfl_down(acc, off, 64);
    if (lane == 0) out[b] = acc;
}

extern "C" void kernel_launch(void* const* d_in, const int* in_sizes, int n_in,
                              void* d_out, int out_size, void* d_ws, size_t ws_size,
                              hipStream_t stream) {
    const float* node_emb = (const float*)d_in[0];
    const float* W        = (const float*)d_in[1];
    const float* bias     = (const float*)d_in[2];
    const float* a_src    = (const float*)d_in[3];
    const float* a_dst    = (const float*)d_in[4];
    const float* a_rel    = (const float*)d_in[5];
    const float* rel_feat = (const float*)d_in[6];
    const float* rel_emb  = (const float*)d_in[7];
    const int* edge_index = (const int*)d_in[8];
    const int* edge_type  = (const int*)d_in[9];
    const int* src_ids    = (const int*)d_in[10];
    const int* rel_ids    = (const int*)d_in[11];
    const int* dst_ids    = (const int*)d_in[12];
    float* out = (float*)d_out;

    char* w = (char*)d_ws;
    auto alloc = [&](size_t bytes) -> void* {
        void* p = (void*)w;
        w += (bytes + 255) & ~(size_t)255;
        return p;
    };
    int* slot_of_node = (int*)alloc((size_t)NN * 4);
    int* xrow_of_node = (int*)alloc((size_t)NN * 4);
    int* scorelist    = (int*)alloc((size_t)SLOT_CAP * 4);
    int* rows         = (int*)alloc((size_t)NN * 4);
    int* counters     = (int*)alloc(256);
    int* deg          = (int*)alloc((size_t)SLOT_CAP * 4);
    int* base         = (int*)alloc((size_t)SLOT_CAP * 4);
    int* cursor       = (int*)alloc((size_t)SLOT_CAP * 4);
    int* tlist        = (int*)alloc((size_t)EE * 4);
    float* clogit = (float*)alloc((size_t)EE * 4 * 4);
    float* sS     = (float*)alloc((size_t)SRC_CAP * 4 * 4);
    float* sD     = (float*)alloc((size_t)SRC_CAP * 4 * 4);
    float* Wa     = (float*)alloc((size_t)IN_DIM * 8 * 4);
    float* prel   = (float*)alloc((size_t)NUM_REL * 4 * 4);
    unsigned short* Wt    = (unsigned short*)alloc((size_t)7 * 32 * 512 * 8 * 2);
    unsigned short* h_src = (unsigned short*)alloc((size_t)SRC_CAP * HID * 2);
    float* refined = (float*)alloc((size_t)SLOT_CAP * HID * 4);

    int wa_blocks = (IN_DIM * 8 + NUM_REL * HEADS + 3) / 4;
    k_init_wa<<<INIT_BLOCKS + wa_blocks, 256, 0, stream>>>(
        slot_of_node, xrow_of_node, deg, counters,
        W, a_src, a_dst, a_rel, rel_feat, Wa, prel);
    k_build_slots<<<(2 * BB + 255) / 256, 256, 0, stream>>>(src_ids, dst_ids, slot_of_node,
                                                            counters, scorelist);
    k_edge0<<<(EE + 255) / 256, 256, 0, stream>>>(edge_index, slot_of_node,
                                                  xrow_of_node, counters, rows, deg);
    k_tail_scan_wt<<<65 + 224, 256, 0, stream>>>(scorelist, xrow_of_node, counters,
                                                 rows, deg, base, cursor, W, Wa, Wt);
    dim3 ggrid(7, 392);
    k_hgemm<<<ggrid, 256, 0, stream>>>(node_emb, rows, Wt, counters, h_src, sS, sD);
    k_place<<<(EE + 255) / 256, 256, 0, stream>>>(edge_index, edge_type, slot_of_node,
                                                  xrow_of_node, cursor, sS, sD, prel,
                                                  clogit, tlist);
    k_aggregate<<<SLOT_CAP, 256, 0, stream>>>(counters, base, deg, tlist,
                                              clogit, h_src, bias, refined);
    k_score<<<(BB * 64 + 255) / 256, 256, 0, stream>>>(src_ids, rel_ids, dst_ids,
                                                       slot_of_node, rel_emb, refined, out);
}

// Round 6
// 449.466 us; speedup vs baseline: 1.1238x; 1.0257x over previous
//
#include <hip/hip_runtime.h>
#include <hip/hip_bf16.h>
#include <math.h>

#define NN 50000
#define IN_DIM 1024
#define EE 100000
#define NUM_REL 40
#define HEADS 4
#define OUT_D 200
#define HID 800
#define BB 8192
#define SLOT_CAP 16384
#define SRC_CAP 50176   // max gathered rows (>= NN rounded to tile)

typedef __attribute__((ext_vector_type(8))) short short8;
typedef __attribute__((ext_vector_type(4))) float f32x4;
typedef __attribute__((ext_vector_type(2))) unsigned int u32x2;

__device__ inline unsigned short f2bf(float f) {
    unsigned int u = __float_as_uint(f);
    u += 0x7FFF + ((u >> 16) & 1);
    return (unsigned short)(u >> 16);
}
__device__ inline float bf2f(unsigned short s) {
    return __uint_as_float(((unsigned int)s) << 16);
}
__device__ inline void gl2lds16(const unsigned short* g, unsigned short* l) {
    __builtin_amdgcn_global_load_lds(
        (const __attribute__((address_space(1))) void*)g,
        (__attribute__((address_space(3))) void*)l, 16, 0, 0);
}
// packed f32x4 -> 4 bf16 (RNE, matches f2bf); no builtin on gfx950
__device__ inline u32x2 cvt4(float4 v) {
    u32x2 r;
    asm("v_cvt_pk_bf16_f32 %0, %1, %2" : "=v"(r.x) : "v"(v.x), "v"(v.y));
    asm("v_cvt_pk_bf16_f32 %0, %1, %2" : "=v"(r.y) : "v"(v.z), "v"(v.w));
    return r;
}

// wave-aggregated compaction: one atomicAdd per wave instead of per winner.
__device__ inline int wave_compact(bool won, int* ctr) {
    unsigned long long m = __ballot(won);
    if (!m) return -1;
    int lane = threadIdx.x & 63;
    int leader = __ffsll((long long)m) - 1;
    int base = 0;
    if (lane == leader) base = atomicAdd(ctr, __popcll(m));
    base = __shfl(base, leader, 64);
    return won ? base + __popcll(m & ((1ull << lane) - 1)) : -1;
}

// ---------------- fused: init (blocks 0..195) | Wa/prel (blocks 196..) ----------------
#define INIT_BLOCKS 196
__global__ __launch_bounds__(256) void k_init_wa(int* slot_of_node, int* xrow_of_node,
                                                 int* deg, int* counters,
                                                 const float* W, const float* a_src,
                                                 const float* a_dst, const float* a_rel,
                                                 const float* rel_feat, float* Wa, float* prel) {
    int b = blockIdx.x;
    if (b < INIT_BLOCKS) {
        int i = b * 256 + threadIdx.x;
        if (i < NN) { slot_of_node[i] = -1; xrow_of_node[i] = -1; }
        if (i < SLOT_CAP) deg[i] = 0;
        if (i < 8) counters[i] = 0;
        return;
    }
    int wid = (b - INIT_BLOCKS) * 4 + (threadIdx.x >> 6);
    int lane = threadIdx.x & 63;
    if (wid >= IN_DIM * 8 + NUM_REL * HEADS) return;
    float acc = 0.f;
    int d = lane * 4;
    if (d < OUT_D) {
        const float* row;
        const float* a;
        if (wid < IN_DIM * 8) {
            int k = wid >> 3, c = wid & 7;
            int h = c & 3;
            row = W + (size_t)k * HID + h * OUT_D;
            a = ((c < 4) ? a_src : a_dst) + h * OUT_D;
        } else {
            int j = wid - IN_DIM * 8;
            int r = j >> 2, h = j & 3;
            row = rel_feat + (size_t)r * HID + h * OUT_D;
            a = a_rel + h * OUT_D;
        }
        float4 wv = *(const float4*)(row + d);
        float4 av = *(const float4*)(a + d);
        acc = wv.x * av.x + wv.y * av.y + wv.z * av.z + wv.w * av.w;
    }
    for (int off = 32; off; off >>= 1) acc += __shfl_down(acc, off, 64);
    if (lane == 0) {
        if (wid < IN_DIM * 8) Wa[wid] = acc;
        else prel[wid - IN_DIM * 8] = acc;
    }
}

// compact score nodes (src_ids ∪ dst_ids) -> slots; record unique score list
__global__ void k_build_slots(const int* src_ids, const int* dst_ids,
                              int* slot_of_node, int* counters, int* scorelist) {
    int i = blockIdx.x * 256 + threadIdx.x;
    bool valid = i < 2 * BB;
    int n = 0;
    bool won = false;
    if (valid) {
        n = (i < BB) ? src_ids[i] : dst_ids[i - BB];
        if (slot_of_node[n] == -1)
            won = (atomicCAS(&slot_of_node[n], -1, -2) == -1);
    }
    int s = wave_compact(won, &counters[0]);
    if (won) {
        slot_of_node[n] = s;
        scorelist[s] = n;
    }
}

// survivor pass: compact srcs of surviving edges (xrows 0..nsrc), per-slot degree
__global__ void k_edge0(const int* ei, const int* slot_of_node,
                        int* xrow_of_node, int* counters, int* rows, int* deg) {
    int e = blockIdx.x * 256 + threadIdx.x;
    bool valid = e < EE;
    int slot = -1, sn = 0;
    if (valid) {
        int dn = ei[EE + e];
        slot = slot_of_node[dn];
    }
    bool surv = valid && slot >= 0;
    bool won = false;
    if (surv) {
        sn = ei[e];
        if (xrow_of_node[sn] == -1)
            won = (atomicCAS(&xrow_of_node[sn], -1, -2) == -1);
    }
    int t = wave_compact(won, &counters[1]);
    if (won) {
        rows[t] = sn;
        xrow_of_node[sn] = t;
    }
    if (surv) atomicAdd(&deg[slot], 1);
}

// fused: scan (block 0) | tail (blocks 1..64) | Wt fragment-chunk pack (65..288)
// Wt layout: for coltile n0 (0..6), 32-k step ks (0..31): 512 chunks of 8 bf16,
// chunk c -> col = (c>>6)*16 + (c&15), kc = (c>>4)&3, shorts kj=0..7 hold
// W[ks*32 + kc*8 + kj][n0*128 + col]. EXACTLY the LDS fragment order the GEMM
// consumes -> B staging is fully linear gl2lds.
__global__ __launch_bounds__(256) void k_tail_scan_wt(const int* scorelist, int* xrow_of_node,
                                                      int* counters, int* rows,
                                                      const int* deg, int* base, int* cursor,
                                                      const float* W, const float* Wa,
                                                      unsigned short* Wt) {
    int t = threadIdx.x;
    if (blockIdx.x == 0) {
        __shared__ int pref[257];
        int s = 0;
        const int4* dv = (const int4*)(deg + t * (SLOT_CAP / 256));
        for (int i = 0; i < SLOT_CAP / 256 / 4; ++i) {
            int4 v = dv[i];
            s += v.x + v.y + v.z + v.w;
        }
        pref[t + 1] = s;
        if (t == 0) pref[0] = 0;
        __syncthreads();
        if (t == 0)
            for (int i = 1; i <= 256; ++i) pref[i] += pref[i - 1];
        __syncthreads();
        int r = pref[t];
        for (int i = 0; i < SLOT_CAP / 256; ++i) {
            int idx = t * (SLOT_CAP / 256) + i;
            base[idx] = r;
            cursor[idx] = r;
            r += deg[idx];
        }
        return;
    }
    if (blockIdx.x <= 64) {
        int i = (blockIdx.x - 1) * 256 + t;
        bool valid = i < counters[0];
        int n = 0;
        bool won = false;
        if (valid) {
            n = scorelist[i];
            won = (xrow_of_node[n] < 0);
        }
        int tt = wave_compact(won, &counters[3]);
        if (won) {
            int xr = counters[1] + tt;   // counters[1] stable: edge0 completed
            xrow_of_node[n] = xr;
            rows[xr] = n;
        }
        return;
    }
    int bw = blockIdx.x - 65;            // 0..223 = 7 coltiles x 32 ksteps
    int n0 = bw >> 5, ks = bw & 31;
    unsigned short* dst = Wt + (size_t)(n0 * 32 + ks) * 512 * 8;
#pragma unroll
    for (int q = 0; q < 2; ++q) {
        int c = q * 256 + t;
        int col = ((c >> 6) << 4) + (c & 15);
        int kc = (c >> 4) & 3;
        int gcol = n0 * 128 + col;
        int kbase = ks * 32 + kc * 8;
        unsigned short o[8];
        if (gcol < HID) {
#pragma unroll
            for (int kj = 0; kj < 8; ++kj) o[kj] = f2bf(W[(size_t)(kbase + kj) * HID + gcol]);
        } else if (gcol < HID + 8) {
#pragma unroll
            for (int kj = 0; kj < 8; ++kj) o[kj] = f2bf(Wa[(size_t)(kbase + kj) * 8 + (gcol - HID)]);
        } else {
#pragma unroll
            for (int kj = 0; kj < 8; ++kj) o[kj] = 0;
        }
        *(short8*)(dst + (size_t)c * 8) = *(short8*)o;
    }
}

// MFMA bf16 GEMM — occupancy/sync-sparsity structure.
// 128x128 tile, 512 threads = 8 waves, wave-tile 64x32 (acc[4][2]).
// BK=64 round = 2x 32-k sub-steps, ONE barrier per round (16 rounds).
// A (gather): thread t: rows rA=t>>3, rA+64; lane-exact map — each float4
//   instr covers 8 FULL 128B lines (1 request/line); cvt_pk -> ds_write_b64
//   into fragment chunks. One f32 set, cvt-early (A(r+1) cvt'd at round r).
// B: 1 gl2lds pair per round from chunk-linear Wt (fully sequential).
// Buffers: A x2 (16KB), B x3 (16KB) = 80KB -> 2 blocks/CU = 16 waves/CU.
// Counted gate: vmcnt(6) = A(r+2)[4]+B(r+2)[2] in flight across the barrier.
// XCD swizzle: 2744 = 49 groups of 56; XCD x sweeps row-panel g*8+x across
// its 7 col-tiles (A panel stays in that XCD's L2).
#define GBM 128
#define GBN 128

#define AGLOAD(K) do {                                                  \
    fA0 = *(const float4*)(axA + (size_t)(K) * 64);                     \
    fA1 = *(const float4*)(axA + (size_t)(K) * 64 + 32);                \
    fA2 = *(const float4*)(axB + (size_t)(K) * 64);                     \
    fA3 = *(const float4*)(axB + (size_t)(K) * 64 + 32);                \
} while (0)

#define AWRITE(AS) do {                                                 \
    *(u32x2*)((AS) + wA)            = cvt4(fA0);                        \
    *(u32x2*)((AS) + wA + 512 * 8)  = cvt4(fA1);                        \
    *(u32x2*)((AS) + wB)            = cvt4(fA2);                        \
    *(u32x2*)((AS) + wB + 512 * 8)  = cvt4(fA3);                        \
} while (0)

#define BSTAGE(BS, R) do {                                              \
    gl2lds16(bsrc + ((size_t)(2 * (R)) * 512 + t) * 8,     (BS) + (size_t)t * 8); \
    gl2lds16(bsrc + ((size_t)(2 * (R) + 1) * 512 + t) * 8, (BS) + (size_t)(512 + t) * 8); \
} while (0)

#define COMPUTE(AS, BS) do {                                            \
    _Pragma("unroll")                                                   \
    for (int s = 0; s < 2; ++s) {                                       \
        short8 af[4], bf2r[2];                                          \
        _Pragma("unroll")                                               \
        for (int i = 0; i < 4; ++i)                                     \
            af[i] = *(const short8*)&(AS)[(size_t)(s * 512 + (ga + i) * 64 + lane) * 8]; \
        _Pragma("unroll")                                               \
        for (int j = 0; j < 2; ++j)                                     \
            bf2r[j] = *(const short8*)&(BS)[(size_t)(s * 512 + (gb + j) * 64 + lane) * 8]; \
        __builtin_amdgcn_s_setprio(1);                                  \
        _Pragma("unroll")                                               \
        for (int i = 0; i < 4; ++i)                                     \
            _Pragma("unroll")                                           \
            for (int j = 0; j < 2; ++j)                                 \
                acc[i][j] = __builtin_amdgcn_mfma_f32_16x16x32_bf16(af[i], bf2r[j], acc[i][j], 0, 0, 0); \
        __builtin_amdgcn_s_setprio(0);                                  \
    }                                                                   \
} while (0)

#define WAIT6   asm volatile("s_waitcnt vmcnt(6)" ::: "memory")
#define WAIT4   asm volatile("s_waitcnt vmcnt(4)" ::: "memory")
#define WAIT0   asm volatile("s_waitcnt vmcnt(0)" ::: "memory")
#define PUBBAR  asm volatile("s_waitcnt lgkmcnt(0)\n\ts_barrier" ::: "memory")

__global__ __launch_bounds__(512, 4) void k_hgemm(const float* x, const int* rows,
                                                  const unsigned short* Wt,
                                                  const int* counters, unsigned short* h_src,
                                                  float* sS, float* sD) {
    int nsrc = counters[1];
    int nneed = nsrc + counters[3];
    int lin = blockIdx.x + 7 * blockIdx.y;   // 0..2743 = 49 groups of 56
    int g = lin / 56, r = lin % 56;
    int rowb = g * 8 + (r & 7);              // 0..391
    int colb = r >> 3;                       // 0..6
    int col0 = colb * GBN;
    int row0 = rowb * GBM;
    int rowlim = (colb == 6) ? nneed : nsrc;
    if (row0 >= rowlim) return;
    __shared__ unsigned short As0[8192], As1[8192];              // 16 KB each
    __shared__ unsigned short Bs0[8192], Bs1[8192], Bs2[8192];   // 16 KB each
    int t = threadIdx.x;
    // A gather map: rows rA = t>>3 and rA+64; 8 threads/row, thread j = t&7
    // covers floats [j*4, j*4+4) of each 32-float half (one f4 per half).
    int rA = t >> 3, jo = (t & 7) * 4;
    int lim = nneed - 1;
    const float* axA = x + (size_t)rows[min(row0 + rA,      lim)] * IN_DIM + jo;
    const float* axB = x + (size_t)rows[min(row0 + rA + 64, lim)] * IN_DIM + jo;
    // LDS write offsets (shorts): chunk(row, half, kc=j>>1) + subhalf (j&1)*4
    int jj = t & 7;
    int wA = (((rA >> 4) << 6) + ((jj >> 1) << 4) + (rA & 15)) * 8 + (jj & 1) * 4;
    int rB = rA + 64;
    int wB = (((rB >> 4) << 6) + ((jj >> 1) << 4) + (rB & 15)) * 8 + (jj & 1) * 4;
    const unsigned short* bsrc = Wt + (size_t)colb * 32 * 512 * 8;
    int w = t >> 6, lane = t & 63;
    int ga = (w >> 2) * 4, gb = (w & 3) * 2;
    int wr = (w >> 2) * 64, wc = (w & 3) * 32;
    int fm = lane & 15, fq = lane >> 4;
    float4 fA0, fA1, fA2, fA3;
    f32x4 acc[4][2] = {};
    unsigned short *aC = As0, *aW = As1;
    unsigned short *bA = Bs0, *bB = Bs1, *bC = Bs2;
    // prologue
    AGLOAD(0);                 // 4
    BSTAGE(bA, 0);             // 2
    BSTAGE(bB, 1);             // 2
    WAIT4;                     // A(0) done (B still in flight)
    AWRITE(aC);
    AGLOAD(1);
    WAIT0;                     // A(1), B(0), B(1) done
    PUBBAR;
#pragma unroll 1
    for (int k = 0; k < 14; ++k) {
        AWRITE(aW);            // cvt+write A(k+1) (f32 regs complete)
        AGLOAD(k + 2);         // 4 in flight
        BSTAGE(bC, k + 2);     // 2 in flight
        COMPUTE(aC, bA);
        WAIT6;                 // A(k+2)+B(k+2) stay in flight across barrier
        PUBBAR;
        unsigned short* ta = aC; aC = aW; aW = ta;
        unsigned short* tb = bA; bA = bB; bB = bC; bC = tb;
    }
    // k = 14: nothing new to stage
    AWRITE(aW);                // A(15)
    COMPUTE(aC, bA);
    WAIT0;
    PUBBAR;
    // k = 15
    COMPUTE(aW, bB);
#pragma unroll
    for (int i = 0; i < 4; ++i) {
#pragma unroll
        for (int j = 0; j < 2; ++j) {
            int gcol = col0 + wc + j * 16 + fm;
            if (gcol >= HID + 8) continue;
#pragma unroll
            for (int rr = 0; rr < 4; ++rr) {
                int grow = row0 + wr + i * 16 + fq * 4 + rr;
                float v = acc[i][j][rr];
                if (gcol < HID) {
                    if (grow < nsrc) h_src[(size_t)grow * HID + gcol] = f2bf(v);
                } else if (grow < nneed) {
                    int c = gcol - HID;
                    if (c < 4) sS[grow * 4 + c] = v;
                    else sD[grow * 4 + (c - 4)] = v;
                }
            }
        }
    }
}

// place surviving edges into CSR, computing logits at final position
__global__ void k_place(const int* ei, const int* etype, const int* slot_of_node,
                        const int* xrow_of_node, int* cursor,
                        const float* sS, const float* sD, const float* prel,
                        float* clogit, int* tlist) {
    int e = blockIdx.x * 256 + threadIdx.x;
    if (e >= EE) return;
    int dn = ei[EE + e];
    int slot = slot_of_node[dn];
    if (slot < 0) return;
    int sn = ei[e];
    int r = etype[e];
    int xs = xrow_of_node[sn];
    int xd = xrow_of_node[dn];
    int pos = atomicAdd(&cursor[slot], 1);
    tlist[pos] = xs;
    float4 lg;
    float* lp = (float*)&lg;
#pragma unroll
    for (int h = 0; h < 4; ++h) {
        float v = sS[xs * 4 + h] + sD[xd * 4 + h] + prel[r * 4 + h];
        lp[h] = v > 0.f ? v : 0.2f * v;
    }
    *(float4*)&clogit[(size_t)pos * 4] = lg;
}

// per-dst-slot softmax + aggregate: 4 slots per block (avg degree ~2 makes
// one-block-per-slot dispatch-overhead-dominated); 200 lanes x f4, ushort4 loads
__global__ __launch_bounds__(256) void k_aggregate(const int* counters, const int* base,
                                                   const int* deg, const int* tlist,
                                                   const float* clogit,
                                                   const unsigned short* h_src, const float* bias,
                                                   float* refined) {
    __shared__ float m4[4], den4[4];
    __shared__ float alpha[64][4];
    __shared__ int tsl[64];
    int t = threadIdx.x;
    int nslot = counters[0];
#pragma unroll 1
    for (int s = 0; s < 4; ++s) {
        int b = blockIdx.x * 4 + s;
        __syncthreads();
        if (b >= nslot) continue;
        int beg = base[b], d = deg[b];
        if (t < 4) {
            float m = -3e38f;
            for (int j = 0; j < d; ++j)
                m = fmaxf(m, clogit[(size_t)(beg + j) * 4 + t]);
            float ss = 0.f;
            for (int j = 0; j < d; ++j)
                ss += expf(clogit[(size_t)(beg + j) * 4 + t] - m);
            m4[t] = m;
            den4[t] = ss;
        }
        __syncthreads();
        int head = t / 50;               // (t*4)/200
        float4 acc = {0.f, 0.f, 0.f, 0.f};
        for (int j0 = 0; j0 < d; j0 += 64) {
            int nc = min(64, d - j0);
            if (t < nc * 4) {
                int j = t >> 2, h = t & 3;
                alpha[j][h] = expf(clogit[(size_t)(beg + j0 + j) * 4 + h] - m4[h]) / den4[h];
                if (h == 0) tsl[j] = tlist[beg + j0 + j];
            }
            __syncthreads();
            if (t < 200) {
                for (int j = 0; j < nc; ++j) {
                    float a = alpha[j][head];
                    ushort4 hv = *(const ushort4*)(h_src + (size_t)tsl[j] * HID + t * 4);
                    acc.x += a * bf2f(hv.x);
                    acc.y += a * bf2f(hv.y);
                    acc.z += a * bf2f(hv.z);
                    acc.w += a * bf2f(hv.w);
                }
            }
            __syncthreads();
        }
        if (t < 200) {
            float4 bv = *(const float4*)(bias + t * 4);
            float4 o = {acc.x + bv.x, acc.y + bv.y, acc.z + bv.z, acc.w + bv.w};
            *(float4*)(refined + (size_t)b * HID + t * 4) = o;
        }
    }
}

// DistMult scoring: one wave per triple, float4 loads
__global__ __launch_bounds__(256) void k_score(const int* src_ids, const int* rel_ids,
                                               const int* dst_ids, const int* slot_of_node,
                                               const float* rel_emb, const float* refined,
                                               float* out) {
    int gid = blockIdx.x * 256 + threadIdx.x;
    int b = gid >> 6;
    int lane = threadIdx.x & 63;
    if (b >= BB) return;
    int ss = slot_of_node[src_ids[b]];
    int ds = slot_of_node[dst_ids[b]];
    int r = rel_ids[b];
    const float* sv = refined + (size_t)ss * HID;
    const float* dv = refined + (size_t)ds * HID;
    const float* rv = rel_emb + (size_t)r * HID;
    float acc = 0.f;
    for (int c4 = lane; c4 < 200; c4 += 64) {
        float4 s = *(const float4*)(sv + c4 * 4);
        float4 dq = *(const float4*)(dv + c4 * 4);
        float4 rr = *(const float4*)(rv + c4 * 4);
        acc += s.x * rr.x * dq.x + s.y * rr.y * dq.y + s.z * rr.z * dq.z + s.w * rr.w * dq.w;
    }
    for (int off = 32; off; off >>= 1) acc += __shfl_down(acc, off, 64);
    if (lane == 0) out[b] = acc;
}

extern "C" void kernel_launch(void* const* d_in, const int* in_sizes, int n_in,
                              void* d_out, int out_size, void* d_ws, size_t ws_size,
                              hipStream_t stream) {
    const float* node_emb = (const float*)d_in[0];
    const float* W        = (const float*)d_in[1];
    const float* bias     = (const float*)d_in[2];
    const float* a_src    = (const float*)d_in[3];
    const float* a_dst    = (const float*)d_in[4];
    const float* a_rel    = (const float*)d_in[5];
    const float* rel_feat = (const float*)d_in[6];
    const float* rel_emb  = (const float*)d_in[7];
    const int* edge_index = (const int*)d_in[8];
    const int* edge_type  = (const int*)d_in[9];
    const int* src_ids    = (const int*)d_in[10];
    const int* rel_ids    = (const int*)d_in[11];
    const int* dst_ids    = (const int*)d_in[12];
    float* out = (float*)d_out;

    char* w = (char*)d_ws;
    auto alloc = [&](size_t bytes) -> void* {
        void* p = (void*)w;
        w += (bytes + 255) & ~(size_t)255;
        return p;
    };
    int* slot_of_node = (int*)alloc((size_t)NN * 4);
    int* xrow_of_node = (int*)alloc((size_t)NN * 4);
    int* scorelist    = (int*)alloc((size_t)SLOT_CAP * 4);
    int* rows         = (int*)alloc((size_t)NN * 4);
    int* counters     = (int*)alloc(256);
    int* deg          = (int*)alloc((size_t)SLOT_CAP * 4);
    int* base         = (int*)alloc((size_t)SLOT_CAP * 4);
    int* cursor       = (int*)alloc((size_t)SLOT_CAP * 4);
    int* tlist        = (int*)alloc((size_t)EE * 4);
    float* clogit = (float*)alloc((size_t)EE * 4 * 4);
    float* sS     = (float*)alloc((size_t)SRC_CAP * 4 * 4);
    float* sD     = (float*)alloc((size_t)SRC_CAP * 4 * 4);
    float* Wa     = (float*)alloc((size_t)IN_DIM * 8 * 4);
    float* prel   = (float*)alloc((size_t)NUM_REL * 4 * 4);
    unsigned short* Wt    = (unsigned short*)alloc((size_t)7 * 32 * 512 * 8 * 2);
    unsigned short* h_src = (unsigned short*)alloc((size_t)SRC_CAP * HID * 2);
    float* refined = (float*)alloc((size_t)SLOT_CAP * HID * 4);

    int wa_blocks = (IN_DIM * 8 + NUM_REL * HEADS + 3) / 4;
    k_init_wa<<<INIT_BLOCKS + wa_blocks, 256, 0, stream>>>(
        slot_of_node, xrow_of_node, deg, counters,
        W, a_src, a_dst, a_rel, rel_feat, Wa, prel);
    k_build_slots<<<(2 * BB + 255) / 256, 256, 0, stream>>>(src_ids, dst_ids, slot_of_node,
                                                            counters, scorelist);
    k_edge0<<<(EE + 255) / 256, 256, 0, stream>>>(edge_index, slot_of_node,
                                                  xrow_of_node, counters, rows, deg);
    k_tail_scan_wt<<<65 + 224, 256, 0, stream>>>(scorelist, xrow_of_node, counters,
                                                 rows, deg, base, cursor, W, Wa, Wt);
    dim3 ggrid(7, 392);
    k_hgemm<<<ggrid, 512, 0, stream>>>(node_emb, rows, Wt, counters, h_src, sS, sD);
    k_place<<<(EE + 255) / 256, 256, 0, stream>>>(edge_index, edge_type, slot_of_node,
                                                  xrow_of_node, cursor, sS, sD, prel,
                                                  clogit, tlist);
    k_aggregate<<<SLOT_CAP / 4, 256, 0, stream>>>(counters, base, deg, tlist,
                                                  clogit, h_src, bias, refined);
    k_score<<<(BB * 64 + 255) / 256, 256, 0, stream>>>(src_ids, rel_ids, dst_ids,
                                                       slot_of_node, rel_emb, refined, out);
}